// Round 1
// baseline (1374.065 us; speedup 1.0000x reference)
//
#include <hip/hip_runtime.h>
#include <hip/hip_bf16.h>

#define T_TOK 4096
#define HID   1024
#define FDIM  4096
#define NEXP  8

typedef unsigned short u16;
typedef __attribute__((ext_vector_type(8))) __bf16 bf16x8;
typedef __attribute__((ext_vector_type(4))) float  f32x4;

__device__ __forceinline__ u16 f2bf(float f) {
    unsigned u = __float_as_uint(f);
    u += 0x7fffu + ((u >> 16) & 1u);   // RNE; inputs finite
    return (u16)(u >> 16);
}

// ---------------------------------------------------------------------------
// Kernel 1: router. One 64-thread block per token.
//  - computes 8 fp32 logits (written to d_out logits region)
//  - softmax -> top-2 -> normalized weights
//  - atomic scatter (token, weight) into per-expert lists
//  - casts the token's x row to bf16 into ws
// ---------------------------------------------------------------------------
__global__ __launch_bounds__(64) void router_kernel(
    const float* __restrict__ x, const float* __restrict__ gw,
    float* __restrict__ out_logits, u16* __restrict__ xbf,
    int* __restrict__ counts, int* __restrict__ tokl, float* __restrict__ wtl)
{
    const int t = blockIdx.x;
    const int lane = threadIdx.x;

    const float4* xr = reinterpret_cast<const float4*>(x + (size_t)t * HID);
    float4 xv[4];
#pragma unroll
    for (int j = 0; j < 4; ++j) xv[j] = xr[lane + 64 * j];

    ushort4* xbr = reinterpret_cast<ushort4*>(xbf + (size_t)t * HID);
#pragma unroll
    for (int j = 0; j < 4; ++j) {
        ushort4 u;
        u.x = f2bf(xv[j].x); u.y = f2bf(xv[j].y);
        u.z = f2bf(xv[j].z); u.w = f2bf(xv[j].w);
        xbr[lane + 64 * j] = u;
    }

    float lg[8];
#pragma unroll
    for (int e = 0; e < 8; ++e) {
        const float4* gr = reinterpret_cast<const float4*>(gw + (size_t)e * HID);
        float s = 0.f;
#pragma unroll
        for (int j = 0; j < 4; ++j) {
            float4 g = gr[lane + 64 * j];
            s += xv[j].x * g.x + xv[j].y * g.y + xv[j].z * g.z + xv[j].w * g.w;
        }
#pragma unroll
        for (int off = 32; off >= 1; off >>= 1) s += __shfl_xor(s, off);
        lg[e] = s;
    }

    if (lane == 0) {
#pragma unroll
        for (int e = 0; e < 8; ++e) out_logits[(size_t)t * 8 + e] = lg[e];
        float m = lg[0];
#pragma unroll
        for (int e = 1; e < 8; ++e) m = fmaxf(m, lg[e]);
        float p[8];
#pragma unroll
        for (int e = 0; e < 8; ++e) p[e] = __expf(lg[e] - m);
        // top-2 with jax.lax.top_k tie semantics (earliest index wins)
        int b0 = 0; float v0 = p[0];
#pragma unroll
        for (int e = 1; e < 8; ++e) { if (p[e] > v0) { v0 = p[e]; b0 = e; } }
        int b1 = -1; float v1 = -1.f;
#pragma unroll
        for (int e = 0; e < 8; ++e) { if (e != b0 && p[e] > v1) { v1 = p[e]; b1 = e; } }
        float inv = 1.f / (v0 + v1);
        float w0 = v0 * inv, w1 = v1 * inv;
        int p0 = atomicAdd(&counts[b0], 1);
        tokl[b0 * T_TOK + p0] = t; wtl[b0 * T_TOK + p0] = w0;
        int p1 = atomicAdd(&counts[b1], 1);
        tokl[b1 * T_TOK + p1] = t; wtl[b1 * T_TOK + p1] = w1;
    }
}

__global__ void prefix_kernel(const int* __restrict__ counts, int* __restrict__ offs)
{
    if (threadIdx.x == 0 && blockIdx.x == 0) {
        int s = 0;
        for (int e = 0; e < NEXP; ++e) { offs[e] = s; s += counts[e]; }
        offs[NEXP] = s;
    }
}

// ---------------------------------------------------------------------------
// GEMM1: per expert  H1 = silu(X W1^T) * (X W3^T), bf16 out.
// 128x128 tile, BK=64, 4 waves (2x2 of 64x64), 16x16x32 bf16 MFMA.
// A rows gathered via token list (bf16); W1/W3 fp32 -> bf16 reg-staged.
// LDS XOR-swizzle (byte ^= (row&7)<<4) on all tiles.
// ---------------------------------------------------------------------------
__global__ __launch_bounds__(256, 2) void gemm1_kernel(
    const u16* __restrict__ xbf, const float* __restrict__ gup,
    u16* __restrict__ h1,
    const int* __restrict__ counts, const int* __restrict__ offs,
    const int* __restrict__ tokl)
{
    const int e = blockIdx.z;
    const int cnt = counts[e];
    const int m0 = blockIdx.y * 128;
    if (m0 >= cnt) return;
    const int n0 = blockIdx.x * 128;
    const int tid = threadIdx.x;
    const int lane = tid & 63;
    const int wid = tid >> 6;
    const int wr = wid >> 1, wc = wid & 1;
    int cntL = cnt - m0; if (cntL > 128) cntL = 128;

    __shared__ alignas(16) u16 As[128 * 64];
    __shared__ alignas(16) u16 B1s[128 * 64];
    __shared__ alignas(16) u16 B3s[128 * 64];
    __shared__ int toks[128];

    if (tid < 128)
        toks[tid] = tokl[e * T_TOK + (tid < cntL ? m0 + tid : m0)];
    __syncthreads();

    const float* w1 = gup + ((size_t)e * 2 * FDIM + n0) * HID;
    const float* w3 = w1 + (size_t)FDIM * HID;

    f32x4 accg[4][4], accu[4][4];
#pragma unroll
    for (int i = 0; i < 4; ++i)
#pragma unroll
        for (int j = 0; j < 4; ++j) { accg[i][j] = f32x4{0.f,0.f,0.f,0.f}; accu[i][j] = f32x4{0.f,0.f,0.f,0.f}; }

    for (int k0 = 0; k0 < HID; k0 += 64) {
        // stage A (gathered bf16): 128 rows x 128B = 1024 x 16B chunks
#pragma unroll
        for (int i = 0; i < 4; ++i) {
            int idx = tid + i * 256;
            int row = idx >> 3, c = idx & 7;
            const u16* src = xbf + (size_t)toks[row] * HID + k0 + c * 8;
            int dst = row * 128 + ((c * 16) ^ ((row & 7) << 4));
            *reinterpret_cast<int4*>(reinterpret_cast<char*>(As) + dst) =
                *reinterpret_cast<const int4*>(src);
        }
        // stage B1/B3 (fp32 -> bf16): 128 rows x 16 float4-chunks
#pragma unroll
        for (int i = 0; i < 8; ++i) {
            int idx = tid + i * 256;
            int row = idx >> 4, c4 = idx & 15;
            const float4 f1 = *reinterpret_cast<const float4*>(w1 + (size_t)row * HID + k0 + c4 * 4);
            const float4 f3 = *reinterpret_cast<const float4*>(w3 + (size_t)row * HID + k0 + c4 * 4);
            ushort4 u1; u1.x = f2bf(f1.x); u1.y = f2bf(f1.y); u1.z = f2bf(f1.z); u1.w = f2bf(f1.w);
            ushort4 u3; u3.x = f2bf(f3.x); u3.y = f2bf(f3.y); u3.z = f2bf(f3.z); u3.w = f2bf(f3.w);
            int dst = row * 128 + ((c4 * 8) ^ ((row & 7) << 4));
            *reinterpret_cast<ushort4*>(reinterpret_cast<char*>(B1s) + dst) = u1;
            *reinterpret_cast<ushort4*>(reinterpret_cast<char*>(B3s) + dst) = u3;
        }
        __syncthreads();
#pragma unroll
        for (int kk = 0; kk < 64; kk += 32) {
            bf16x8 a[4], b1[4], b3[4];
            const int colb = (kk + ((lane >> 4) << 3)) * 2;
#pragma unroll
            for (int f = 0; f < 4; ++f) {
                int ra = wr * 64 + f * 16 + (lane & 15);
                a[f] = *reinterpret_cast<const bf16x8*>(reinterpret_cast<const char*>(As) + ra * 128 + (colb ^ ((ra & 7) << 4)));
                int rb = wc * 64 + f * 16 + (lane & 15);
                b1[f] = *reinterpret_cast<const bf16x8*>(reinterpret_cast<const char*>(B1s) + rb * 128 + (colb ^ ((rb & 7) << 4)));
                b3[f] = *reinterpret_cast<const bf16x8*>(reinterpret_cast<const char*>(B3s) + rb * 128 + (colb ^ ((rb & 7) << 4)));
            }
#pragma unroll
            for (int i = 0; i < 4; ++i)
#pragma unroll
                for (int j = 0; j < 4; ++j) {
                    accg[i][j] = __builtin_amdgcn_mfma_f32_16x16x32_bf16(a[i], b1[j], accg[i][j], 0, 0, 0);
                    accu[i][j] = __builtin_amdgcn_mfma_f32_16x16x32_bf16(a[i], b3[j], accu[i][j], 0, 0, 0);
                }
        }
        __syncthreads();
    }

    // epilogue: h = silu(g)*u -> bf16 H1 (compacted rows: offs[e]+m0+row)
    const size_t hbase = (size_t)offs[e] + m0;
#pragma unroll
    for (int i = 0; i < 4; ++i)
#pragma unroll
        for (int j = 0; j < 4; ++j)
#pragma unroll
            for (int v = 0; v < 4; ++v) {
                int rl = wr * 64 + i * 16 + ((lane >> 4) << 2) + v;
                if (rl < cntL) {
                    float g = accg[i][j][v], u = accu[i][j][v];
                    float h = (g / (1.f + __expf(-g))) * u;
                    int cl = wc * 64 + j * 16 + (lane & 15);
                    h1[(hbase + rl) * FDIM + n0 + cl] = f2bf(h);
                }
            }
}

// ---------------------------------------------------------------------------
// GEMM2: per expert  OUT += w_tok * (H1 W2^T). Same structure, K=4096.
// Epilogue: fp32 atomicAdd scatter into d_out.
// ---------------------------------------------------------------------------
__global__ __launch_bounds__(256, 2) void gemm2_kernel(
    const u16* __restrict__ h1, const float* __restrict__ dw,
    float* __restrict__ out,
    const int* __restrict__ counts, const int* __restrict__ offs,
    const int* __restrict__ tokl, const float* __restrict__ wtl)
{
    const int e = blockIdx.z;
    const int cnt = counts[e];
    const int m0 = blockIdx.y * 128;
    if (m0 >= cnt) return;
    const int n0 = blockIdx.x * 128;
    const int tid = threadIdx.x;
    const int lane = tid & 63;
    const int wid = tid >> 6;
    const int wr = wid >> 1, wc = wid & 1;
    int cntL = cnt - m0; if (cntL > 128) cntL = 128;

    __shared__ alignas(16) u16 As[128 * 64];
    __shared__ alignas(16) u16 Bs[128 * 64];
    __shared__ int toks[128];
    __shared__ float wts[128];

    if (tid < 128) {
        int r = (tid < cntL ? m0 + tid : m0);
        toks[tid] = tokl[e * T_TOK + r];
        wts[tid]  = wtl[e * T_TOK + r];
    }
    __syncthreads();

    const size_t hrow0 = (size_t)offs[e] + m0;
    const float* w2 = dw + (size_t)e * HID * FDIM + (size_t)n0 * FDIM;

    f32x4 acc[4][4];
#pragma unroll
    for (int i = 0; i < 4; ++i)
#pragma unroll
        for (int j = 0; j < 4; ++j) acc[i][j] = f32x4{0.f,0.f,0.f,0.f};

    for (int k0 = 0; k0 < FDIM; k0 += 64) {
#pragma unroll
        for (int i = 0; i < 4; ++i) {
            int idx = tid + i * 256;
            int row = idx >> 3, c = idx & 7;
            int rr = (row < cntL ? row : 0);
            const u16* src = h1 + (hrow0 + rr) * FDIM + k0 + c * 8;
            int dst = row * 128 + ((c * 16) ^ ((row & 7) << 4));
            *reinterpret_cast<int4*>(reinterpret_cast<char*>(As) + dst) =
                *reinterpret_cast<const int4*>(src);
        }
#pragma unroll
        for (int i = 0; i < 8; ++i) {
            int idx = tid + i * 256;
            int row = idx >> 4, c4 = idx & 15;
            const float4 f = *reinterpret_cast<const float4*>(w2 + (size_t)row * FDIM + k0 + c4 * 4);
            ushort4 u; u.x = f2bf(f.x); u.y = f2bf(f.y); u.z = f2bf(f.z); u.w = f2bf(f.w);
            int dst = row * 128 + ((c4 * 8) ^ ((row & 7) << 4));
            *reinterpret_cast<ushort4*>(reinterpret_cast<char*>(Bs) + dst) = u;
        }
        __syncthreads();
#pragma unroll
        for (int kk = 0; kk < 64; kk += 32) {
            bf16x8 a[4], b[4];
            const int colb = (kk + ((lane >> 4) << 3)) * 2;
#pragma unroll
            for (int f = 0; f < 4; ++f) {
                int ra = wr * 64 + f * 16 + (lane & 15);
                a[f] = *reinterpret_cast<const bf16x8*>(reinterpret_cast<const char*>(As) + ra * 128 + (colb ^ ((ra & 7) << 4)));
                int rb = wc * 64 + f * 16 + (lane & 15);
                b[f] = *reinterpret_cast<const bf16x8*>(reinterpret_cast<const char*>(Bs) + rb * 128 + (colb ^ ((rb & 7) << 4)));
            }
#pragma unroll
            for (int i = 0; i < 4; ++i)
#pragma unroll
                for (int j = 0; j < 4; ++j)
                    acc[i][j] = __builtin_amdgcn_mfma_f32_16x16x32_bf16(a[i], b[j], acc[i][j], 0, 0, 0);
        }
        __syncthreads();
    }

#pragma unroll
    for (int i = 0; i < 4; ++i)
#pragma unroll
        for (int j = 0; j < 4; ++j)
#pragma unroll
            for (int v = 0; v < 4; ++v) {
                int rl = wr * 64 + i * 16 + ((lane >> 4) << 2) + v;
                if (rl < cntL) {
                    int t = toks[rl];
                    float w = wts[rl];
                    int cl = wc * 64 + j * 16 + (lane & 15);
                    atomicAdd(&out[(size_t)t * HID + n0 + cl], w * acc[i][j][v]);
                }
            }
}

// ---------------------------------------------------------------------------
extern "C" void kernel_launch(void* const* d_in, const int* in_sizes, int n_in,
                              void* d_out, int out_size, void* d_ws, size_t ws_size,
                              hipStream_t stream)
{
    const float* x   = (const float*)d_in[0];
    const float* gw  = (const float*)d_in[1];
    const float* gup = (const float*)d_in[2];
    const float* dw  = (const float*)d_in[3];
    float* out = (float*)d_out;

    char* ws = (char*)d_ws;
    u16*   xbf    = (u16*)ws;                                            // 8 MiB
    u16*   h1     = (u16*)(ws + ((size_t)8 << 20));                      // 64 MiB
    int*   tokl   = (int*)(ws + ((size_t)72 << 20));                     // 128 KiB
    float* wtl    = (float*)(ws + ((size_t)72 << 20) + (128u << 10));    // 128 KiB
    int*   counts = (int*)(ws + ((size_t)72 << 20) + (256u << 10));      // 16 ints
    int*   offs   = counts + 16;                                         // 9 ints

    hipMemsetAsync(counts, 0, 64, stream);
    hipMemsetAsync(d_out, 0, (size_t)T_TOK * HID * sizeof(float), stream);

    router_kernel<<<T_TOK, 64, 0, stream>>>(x, gw, out + (size_t)T_TOK * HID,
                                            xbf, counts, tokl, wtl);
    prefix_kernel<<<1, 64, 0, stream>>>(counts, offs);

    dim3 g1(FDIM / 128, T_TOK / 128, NEXP);
    gemm1_kernel<<<g1, 256, 0, stream>>>(xbf, gup, h1, counts, offs, tokl);

    dim3 g2(HID / 128, T_TOK / 128, NEXP);
    gemm2_kernel<<<g2, 256, 0, stream>>>(h1, dw, out, counts, offs, tokl, wtl);
}

// Round 4
// 935.062 us; speedup vs baseline: 1.4695x; 1.4695x over previous
//
#include <hip/hip_runtime.h>
#include <hip/hip_bf16.h>

#define T_TOK 4096
#define HID   1024
#define FDIM  4096
#define NEXP  8

typedef unsigned short u16;
typedef __attribute__((ext_vector_type(8))) __bf16 bf16x8;
typedef __attribute__((ext_vector_type(4))) float  f32x4;

__device__ __forceinline__ u16 f2bf(float f) {
    unsigned u = __float_as_uint(f);
    u += 0x7fffu + ((u >> 16) & 1u);   // RNE; inputs finite
    return (u16)(u >> 16);
}

// async global->LDS, 16B per lane. LDS dest must be wave-uniform base;
// HW writes base + lane*16. Global src is per-lane.
__device__ __forceinline__ void gl2lds16(const u16* g, u16* l) {
    __builtin_amdgcn_global_load_lds(
        (const __attribute__((address_space(1))) void*)g,
        (__attribute__((address_space(3))) void*)l, 16, 0, 0);
}

// ---------------------------------------------------------------------------
// fp32 -> bf16 weight conversion (once per call; ws re-poisoned every launch)
// ---------------------------------------------------------------------------
__global__ __launch_bounds__(256) void convert_kernel(
    const float* __restrict__ src, u16* __restrict__ dst, int n4)
{
    const int stride = gridDim.x * blockDim.x;
    for (int i = blockIdx.x * blockDim.x + threadIdx.x; i < n4; i += stride) {
        float4 f = reinterpret_cast<const float4*>(src)[i];
        ushort4 u;
        u.x = f2bf(f.x); u.y = f2bf(f.y); u.z = f2bf(f.z); u.w = f2bf(f.w);
        reinterpret_cast<ushort4*>(dst)[i] = u;
    }
}

// ---------------------------------------------------------------------------
// Router: one 64-thread block per token. fp32 logits -> d_out, softmax,
// top-2, normalized weights, atomic scatter to per-expert lists, x -> bf16.
// ---------------------------------------------------------------------------
__global__ __launch_bounds__(64) void router_kernel(
    const float* __restrict__ x, const float* __restrict__ gw,
    float* __restrict__ out_logits, u16* __restrict__ xbf,
    int* __restrict__ counts, int* __restrict__ tokl, float* __restrict__ wtl)
{
    const int t = blockIdx.x;
    const int lane = threadIdx.x;

    const float4* xr = reinterpret_cast<const float4*>(x + (size_t)t * HID);
    float4 xv[4];
#pragma unroll
    for (int j = 0; j < 4; ++j) xv[j] = xr[lane + 64 * j];

    ushort4* xbr = reinterpret_cast<ushort4*>(xbf + (size_t)t * HID);
#pragma unroll
    for (int j = 0; j < 4; ++j) {
        ushort4 u;
        u.x = f2bf(xv[j].x); u.y = f2bf(xv[j].y);
        u.z = f2bf(xv[j].z); u.w = f2bf(xv[j].w);
        xbr[lane + 64 * j] = u;
    }

    float lg[8];
#pragma unroll
    for (int e = 0; e < 8; ++e) {
        const float4* gr = reinterpret_cast<const float4*>(gw + (size_t)e * HID);
        float s = 0.f;
#pragma unroll
        for (int j = 0; j < 4; ++j) {
            float4 g = gr[lane + 64 * j];
            s += xv[j].x * g.x + xv[j].y * g.y + xv[j].z * g.z + xv[j].w * g.w;
        }
#pragma unroll
        for (int off = 32; off >= 1; off >>= 1) s += __shfl_xor(s, off);
        lg[e] = s;
    }

    if (lane == 0) {
#pragma unroll
        for (int e = 0; e < 8; ++e) out_logits[(size_t)t * 8 + e] = lg[e];
        float m = lg[0];
#pragma unroll
        for (int e = 1; e < 8; ++e) m = fmaxf(m, lg[e]);
        float p[8];
#pragma unroll
        for (int e = 0; e < 8; ++e) p[e] = __expf(lg[e] - m);
        int b0 = 0; float v0 = p[0];
#pragma unroll
        for (int e = 1; e < 8; ++e) { if (p[e] > v0) { v0 = p[e]; b0 = e; } }
        int b1 = -1; float v1 = -1.f;
#pragma unroll
        for (int e = 0; e < 8; ++e) { if (e != b0 && p[e] > v1) { v1 = p[e]; b1 = e; } }
        float inv = 1.f / (v0 + v1);
        int p0 = atomicAdd(&counts[b0], 1);
        tokl[b0 * T_TOK + p0] = t; wtl[b0 * T_TOK + p0] = v0 * inv;
        int p1 = atomicAdd(&counts[b1], 1);
        tokl[b1 * T_TOK + p1] = t; wtl[b1 * T_TOK + p1] = v1 * inv;
    }
}

__global__ void prefix_kernel(const int* __restrict__ counts, int* __restrict__ offs)
{
    if (threadIdx.x == 0 && blockIdx.x == 0) {
        int s = 0;
        for (int e = 0; e < NEXP; ++e) { offs[e] = s; s += counts[e]; }
        offs[NEXP] = s;
    }
}

// ===========================================================================
// FAST PATH: bf16 weights pre-converted; m97 structure (global_load_lds w16,
// linear LDS, 2-barrier loop, 128x128 tile, BK=64, 4 waves 2x2).
// ===========================================================================
__global__ __launch_bounds__(256, 2) void gemm1_kernel(
    const u16* __restrict__ xbf, const u16* __restrict__ gupbf,
    u16* __restrict__ h1,
    const int* __restrict__ counts, const int* __restrict__ offs,
    const int* __restrict__ tokl)
{
    const int e = blockIdx.z;
    const int cnt = counts[e];
    const int m0 = blockIdx.y * 128;
    if (m0 >= cnt) return;
    const int n0 = blockIdx.x * 128;
    const int tid = threadIdx.x;
    const int lane = tid & 63;
    const int wid = tid >> 6;
    const int wr = wid >> 1, wc = wid & 1;
    int cntL = cnt - m0; if (cntL > 128) cntL = 128;

    __shared__ alignas(16) u16 As[128 * 64];
    __shared__ alignas(16) u16 B1s[128 * 64];
    __shared__ alignas(16) u16 B3s[128 * 64];
    __shared__ int toks[128];

    if (tid < 128)
        toks[tid] = tokl[e * T_TOK + (tid < cntL ? m0 + tid : m0)];
    __syncthreads();

    const u16* w1 = gupbf + ((size_t)e * 2 * FDIM + n0) * HID;
    const u16* w3 = w1 + (size_t)FDIM * HID;

    // staging: wave w, sub-iter i covers 8 rows starting at (w*4+i)*8.
    // lane l -> row rb+(l>>3), 16B chunk (l&7); LDS linear = base + l*16.
    const int lr = lane >> 3;
    const int lc = (lane & 7) * 8;
    int rb[4]; size_t aOff[4], bOff[4];
#pragma unroll
    for (int i = 0; i < 4; ++i) {
        rb[i] = (wid * 4 + i) * 8;
        aOff[i] = (size_t)toks[rb[i] + lr] * HID + lc;
        bOff[i] = (size_t)(rb[i] + lr) * HID + lc;
    }

    f32x4 accg[4][4], accu[4][4];
#pragma unroll
    for (int i = 0; i < 4; ++i)
#pragma unroll
        for (int j = 0; j < 4; ++j) {
            accg[i][j] = f32x4{0.f, 0.f, 0.f, 0.f};
            accu[i][j] = f32x4{0.f, 0.f, 0.f, 0.f};
        }

    for (int k0 = 0; k0 < HID; k0 += 64) {
#pragma unroll
        for (int i = 0; i < 4; ++i) {
            gl2lds16(xbf + aOff[i] + k0, &As[rb[i] * 64]);
            gl2lds16(w1 + bOff[i] + k0, &B1s[rb[i] * 64]);
            gl2lds16(w3 + bOff[i] + k0, &B3s[rb[i] * 64]);
        }
        __syncthreads();
#pragma unroll
        for (int kk = 0; kk < 64; kk += 32) {
            bf16x8 a[4], b1[4], b3[4];
            const int co = kk + ((lane >> 4) << 3);
#pragma unroll
            for (int f = 0; f < 4; ++f) {
                int ra = wr * 64 + f * 16 + (lane & 15);
                a[f]  = *reinterpret_cast<const bf16x8*>(&As[ra * 64 + co]);
                int rq = wc * 64 + f * 16 + (lane & 15);
                b1[f] = *reinterpret_cast<const bf16x8*>(&B1s[rq * 64 + co]);
                b3[f] = *reinterpret_cast<const bf16x8*>(&B3s[rq * 64 + co]);
            }
#pragma unroll
            for (int i = 0; i < 4; ++i)
#pragma unroll
                for (int j = 0; j < 4; ++j) {
                    accg[i][j] = __builtin_amdgcn_mfma_f32_16x16x32_bf16(a[i], b1[j], accg[i][j], 0, 0, 0);
                    accu[i][j] = __builtin_amdgcn_mfma_f32_16x16x32_bf16(a[i], b3[j], accu[i][j], 0, 0, 0);
                }
        }
        __syncthreads();
    }

    const size_t hbase = (size_t)offs[e] + m0;
#pragma unroll
    for (int i = 0; i < 4; ++i)
#pragma unroll
        for (int j = 0; j < 4; ++j)
#pragma unroll
            for (int v = 0; v < 4; ++v) {
                int rl = wr * 64 + i * 16 + ((lane >> 4) << 2) + v;
                if (rl < cntL) {
                    float g = accg[i][j][v], u = accu[i][j][v];
                    float h = (g / (1.f + __expf(-g))) * u;
                    int cl = wc * 64 + j * 16 + (lane & 15);
                    h1[(hbase + rl) * FDIM + n0 + cl] = f2bf(h);
                }
            }
}

__global__ __launch_bounds__(256, 2) void gemm2_kernel(
    const u16* __restrict__ h1, const u16* __restrict__ dwbf,
    float* __restrict__ out,
    const int* __restrict__ counts, const int* __restrict__ offs,
    const int* __restrict__ tokl, const float* __restrict__ wtl)
{
    const int e = blockIdx.z;
    const int cnt = counts[e];
    const int m0 = blockIdx.y * 128;
    if (m0 >= cnt) return;
    const int n0 = blockIdx.x * 128;
    const int tid = threadIdx.x;
    const int lane = tid & 63;
    const int wid = tid >> 6;
    const int wr = wid >> 1, wc = wid & 1;
    int cntL = cnt - m0; if (cntL > 128) cntL = 128;

    __shared__ alignas(16) u16 As[128 * 64];
    __shared__ alignas(16) u16 Bs[128 * 64];
    __shared__ int toks[128];
    __shared__ float wts[128];

    if (tid < 128) {
        int r = (tid < cntL ? m0 + tid : m0);
        toks[tid] = tokl[e * T_TOK + r];
        wts[tid]  = wtl[e * T_TOK + r];
    }
    __syncthreads();

    const size_t hrow0 = (size_t)offs[e] + m0;
    const u16* w2 = dwbf + (size_t)e * HID * FDIM + (size_t)n0 * FDIM;

    const int lr = lane >> 3;
    const int lc = (lane & 7) * 8;
    int rb[4]; size_t aOff[4], bOff[4];
#pragma unroll
    for (int i = 0; i < 4; ++i) {
        rb[i] = (wid * 4 + i) * 8;
        int r = rb[i] + lr; if (r >= cntL) r = cntL - 1;
        aOff[i] = (hrow0 + r) * (size_t)FDIM + lc;
        bOff[i] = (size_t)(rb[i] + lr) * FDIM + lc;
    }

    f32x4 acc[4][4];
#pragma unroll
    for (int i = 0; i < 4; ++i)
#pragma unroll
        for (int j = 0; j < 4; ++j) acc[i][j] = f32x4{0.f, 0.f, 0.f, 0.f};

    for (int k0 = 0; k0 < FDIM; k0 += 64) {
#pragma unroll
        for (int i = 0; i < 4; ++i) {
            gl2lds16(h1 + aOff[i] + k0, &As[rb[i] * 64]);
            gl2lds16(w2 + bOff[i] + k0, &Bs[rb[i] * 64]);
        }
        __syncthreads();
#pragma unroll
        for (int kk = 0; kk < 64; kk += 32) {
            bf16x8 a[4], b[4];
            const int co = kk + ((lane >> 4) << 3);
#pragma unroll
            for (int f = 0; f < 4; ++f) {
                int ra = wr * 64 + f * 16 + (lane & 15);
                a[f] = *reinterpret_cast<const bf16x8*>(&As[ra * 64 + co]);
                int rq = wc * 64 + f * 16 + (lane & 15);
                b[f] = *reinterpret_cast<const bf16x8*>(&Bs[rq * 64 + co]);
            }
#pragma unroll
            for (int i = 0; i < 4; ++i)
#pragma unroll
                for (int j = 0; j < 4; ++j)
                    acc[i][j] = __builtin_amdgcn_mfma_f32_16x16x32_bf16(a[i], b[j], acc[i][j], 0, 0, 0);
        }
        __syncthreads();
    }

#pragma unroll
    for (int i = 0; i < 4; ++i)
#pragma unroll
        for (int j = 0; j < 4; ++j)
#pragma unroll
            for (int v = 0; v < 4; ++v) {
                int rl = wr * 64 + i * 16 + ((lane >> 4) << 2) + v;
                if (rl < cntL) {
                    int t = toks[rl];
                    float w = wts[rl];
                    int cl = wc * 64 + j * 16 + (lane & 15);
                    atomicAdd(&out[(size_t)t * HID + n0 + cl], w * acc[i][j][v]);
                }
            }
}

// ===========================================================================
// FALLBACK PATH (validated round-1 kernels): fp32 weights converted in-GEMM,
// reg-staged, XOR-swizzled LDS. Used only if ws_size can't fit bf16 copies.
// ===========================================================================
__global__ __launch_bounds__(256, 2) void gemm1_fb_kernel(
    const u16* __restrict__ xbf, const float* __restrict__ gup,
    u16* __restrict__ h1,
    const int* __restrict__ counts, const int* __restrict__ offs,
    const int* __restrict__ tokl)
{
    const int e = blockIdx.z;
    const int cnt = counts[e];
    const int m0 = blockIdx.y * 128;
    if (m0 >= cnt) return;
    const int n0 = blockIdx.x * 128;
    const int tid = threadIdx.x;
    const int lane = tid & 63;
    const int wid = tid >> 6;
    const int wr = wid >> 1, wc = wid & 1;
    int cntL = cnt - m0; if (cntL > 128) cntL = 128;

    __shared__ alignas(16) u16 As[128 * 64];
    __shared__ alignas(16) u16 B1s[128 * 64];
    __shared__ alignas(16) u16 B3s[128 * 64];
    __shared__ int toks[128];

    if (tid < 128)
        toks[tid] = tokl[e * T_TOK + (tid < cntL ? m0 + tid : m0)];
    __syncthreads();

    const float* w1 = gup + ((size_t)e * 2 * FDIM + n0) * HID;
    const float* w3 = w1 + (size_t)FDIM * HID;

    f32x4 accg[4][4], accu[4][4];
#pragma unroll
    for (int i = 0; i < 4; ++i)
#pragma unroll
        for (int j = 0; j < 4; ++j) { accg[i][j] = f32x4{0.f,0.f,0.f,0.f}; accu[i][j] = f32x4{0.f,0.f,0.f,0.f}; }

    for (int k0 = 0; k0 < HID; k0 += 64) {
#pragma unroll
        for (int i = 0; i < 4; ++i) {
            int idx = tid + i * 256;
            int row = idx >> 3, c = idx & 7;
            const u16* src = xbf + (size_t)toks[row] * HID + k0 + c * 8;
            int dst = row * 128 + ((c * 16) ^ ((row & 7) << 4));
            *reinterpret_cast<int4*>(reinterpret_cast<char*>(As) + dst) =
                *reinterpret_cast<const int4*>(src);
        }
#pragma unroll
        for (int i = 0; i < 8; ++i) {
            int idx = tid + i * 256;
            int row = idx >> 4, c4 = idx & 15;
            const float4 f1 = *reinterpret_cast<const float4*>(w1 + (size_t)row * HID + k0 + c4 * 4);
            const float4 f3 = *reinterpret_cast<const float4*>(w3 + (size_t)row * HID + k0 + c4 * 4);
            ushort4 u1; u1.x = f2bf(f1.x); u1.y = f2bf(f1.y); u1.z = f2bf(f1.z); u1.w = f2bf(f1.w);
            ushort4 u3; u3.x = f2bf(f3.x); u3.y = f2bf(f3.y); u3.z = f2bf(f3.z); u3.w = f2bf(f3.w);
            int dst = row * 128 + ((c4 * 8) ^ ((row & 7) << 4));
            *reinterpret_cast<ushort4*>(reinterpret_cast<char*>(B1s) + dst) = u1;
            *reinterpret_cast<ushort4*>(reinterpret_cast<char*>(B3s) + dst) = u3;
        }
        __syncthreads();
#pragma unroll
        for (int kk = 0; kk < 64; kk += 32) {
            bf16x8 a[4], b1[4], b3[4];
            const int colb = (kk + ((lane >> 4) << 3)) * 2;
#pragma unroll
            for (int f = 0; f < 4; ++f) {
                int ra = wr * 64 + f * 16 + (lane & 15);
                a[f] = *reinterpret_cast<const bf16x8*>(reinterpret_cast<const char*>(As) + ra * 128 + (colb ^ ((ra & 7) << 4)));
                int rq = wc * 64 + f * 16 + (lane & 15);
                b1[f] = *reinterpret_cast<const bf16x8*>(reinterpret_cast<const char*>(B1s) + rq * 128 + (colb ^ ((rq & 7) << 4)));
                b3[f] = *reinterpret_cast<const bf16x8*>(reinterpret_cast<const char*>(B3s) + rq * 128 + (colb ^ ((rq & 7) << 4)));
            }
#pragma unroll
            for (int i = 0; i < 4; ++i)
#pragma unroll
                for (int j = 0; j < 4; ++j) {
                    accg[i][j] = __builtin_amdgcn_mfma_f32_16x16x32_bf16(a[i], b1[j], accg[i][j], 0, 0, 0);
                    accu[i][j] = __builtin_amdgcn_mfma_f32_16x16x32_bf16(a[i], b3[j], accu[i][j], 0, 0, 0);
                }
        }
        __syncthreads();
    }

    const size_t hbase = (size_t)offs[e] + m0;
#pragma unroll
    for (int i = 0; i < 4; ++i)
#pragma unroll
        for (int j = 0; j < 4; ++j)
#pragma unroll
            for (int v = 0; v < 4; ++v) {
                int rl = wr * 64 + i * 16 + ((lane >> 4) << 2) + v;
                if (rl < cntL) {
                    float g = accg[i][j][v], u = accu[i][j][v];
                    float h = (g / (1.f + __expf(-g))) * u;
                    int cl = wc * 64 + j * 16 + (lane & 15);
                    h1[(hbase + rl) * FDIM + n0 + cl] = f2bf(h);
                }
            }
}

__global__ __launch_bounds__(256, 2) void gemm2_fb_kernel(
    const u16* __restrict__ h1, const float* __restrict__ dw,
    float* __restrict__ out,
    const int* __restrict__ counts, const int* __restrict__ offs,
    const int* __restrict__ tokl, const float* __restrict__ wtl)
{
    const int e = blockIdx.z;
    const int cnt = counts[e];
    const int m0 = blockIdx.y * 128;
    if (m0 >= cnt) return;
    const int n0 = blockIdx.x * 128;
    const int tid = threadIdx.x;
    const int lane = tid & 63;
    const int wid = tid >> 6;
    const int wr = wid >> 1, wc = wid & 1;
    int cntL = cnt - m0; if (cntL > 128) cntL = 128;

    __shared__ alignas(16) u16 As[128 * 64];
    __shared__ alignas(16) u16 Bs[128 * 64];
    __shared__ int toks[128];
    __shared__ float wts[128];

    if (tid < 128) {
        int r = (tid < cntL ? m0 + tid : m0);
        toks[tid] = tokl[e * T_TOK + r];
        wts[tid]  = wtl[e * T_TOK + r];
    }
    __syncthreads();

    const size_t hrow0 = (size_t)offs[e] + m0;
    const float* w2 = dw + (size_t)e * HID * FDIM + (size_t)n0 * FDIM;

    f32x4 acc[4][4];
#pragma unroll
    for (int i = 0; i < 4; ++i)
#pragma unroll
        for (int j = 0; j < 4; ++j) acc[i][j] = f32x4{0.f,0.f,0.f,0.f};

    for (int k0 = 0; k0 < FDIM; k0 += 64) {
#pragma unroll
        for (int i = 0; i < 4; ++i) {
            int idx = tid + i * 256;
            int row = idx >> 3, c = idx & 7;
            int rr = (row < cntL ? row : 0);
            const u16* src = h1 + (hrow0 + rr) * FDIM + k0 + c * 8;
            int dst = row * 128 + ((c * 16) ^ ((row & 7) << 4));
            *reinterpret_cast<int4*>(reinterpret_cast<char*>(As) + dst) =
                *reinterpret_cast<const int4*>(src);
        }
#pragma unroll
        for (int i = 0; i < 8; ++i) {
            int idx = tid + i * 256;
            int row = idx >> 4, c4 = idx & 15;
            const float4 f = *reinterpret_cast<const float4*>(w2 + (size_t)row * FDIM + k0 + c4 * 4);
            ushort4 u; u.x = f2bf(f.x); u.y = f2bf(f.y); u.z = f2bf(f.z); u.w = f2bf(f.w);
            int dst = row * 128 + ((c4 * 8) ^ ((row & 7) << 4));
            *reinterpret_cast<ushort4*>(reinterpret_cast<char*>(Bs) + dst) = u;
        }
        __syncthreads();
#pragma unroll
        for (int kk = 0; kk < 64; kk += 32) {
            bf16x8 a[4], b[4];
            const int colb = (kk + ((lane >> 4) << 3)) * 2;
#pragma unroll
            for (int f = 0; f < 4; ++f) {
                int ra = wr * 64 + f * 16 + (lane & 15);
                a[f] = *reinterpret_cast<const bf16x8*>(reinterpret_cast<const char*>(As) + ra * 128 + (colb ^ ((ra & 7) << 4)));
                int rq = wc * 64 + f * 16 + (lane & 15);
                b[f] = *reinterpret_cast<const bf16x8*>(reinterpret_cast<const char*>(Bs) + rq * 128 + (colb ^ ((rq & 7) << 4)));
            }
#pragma unroll
            for (int i = 0; i < 4; ++i)
#pragma unroll
                for (int j = 0; j < 4; ++j)
                    acc[i][j] = __builtin_amdgcn_mfma_f32_16x16x32_bf16(a[i], b[j], acc[i][j], 0, 0, 0);
        }
        __syncthreads();
    }

#pragma unroll
    for (int i = 0; i < 4; ++i)
#pragma unroll
        for (int j = 0; j < 4; ++j)
#pragma unroll
            for (int v = 0; v < 4; ++v) {
                int rl = wr * 64 + i * 16 + ((lane >> 4) << 2) + v;
                if (rl < cntL) {
                    int t = toks[rl];
                    float w = wts[rl];
                    int cl = wc * 64 + j * 16 + (lane & 15);
                    atomicAdd(&out[(size_t)t * HID + n0 + cl], w * acc[i][j][v]);
                }
            }
}

// ---------------------------------------------------------------------------
extern "C" void kernel_launch(void* const* d_in, const int* in_sizes, int n_in,
                              void* d_out, int out_size, void* d_ws, size_t ws_size,
                              hipStream_t stream)
{
    const float* x   = (const float*)d_in[0];
    const float* gw  = (const float*)d_in[1];
    const float* gup = (const float*)d_in[2];
    const float* dw  = (const float*)d_in[3];
    float* out = (float*)d_out;

    const size_t FAST_NEED = ((size_t)264 << 20) + (512u << 10);
    const bool fast = ws_size >= FAST_NEED;

    char* ws = (char*)d_ws;
    u16* xbf   = (u16*)ws;                              // 8 MiB
    u16* h1    = (u16*)(ws + ((size_t)8 << 20));        // 64 MiB
    u16* gupbf = (u16*)(ws + ((size_t)72 << 20));       // 128 MiB (fast only)
    u16* dwbf  = (u16*)(ws + ((size_t)200 << 20));      // 64 MiB  (fast only)
    // control block: end-relative when fallback, fixed when fast
    size_t ctrl = fast ? ((size_t)264 << 20) : ((size_t)72 << 20);
    int*   tokl   = (int*)(ws + ctrl);                  // 128 KiB
    float* wtl    = (float*)(ws + ctrl + (128u << 10)); // 128 KiB
    int*   counts = (int*)(ws + ctrl + (256u << 10));
    int*   offs   = counts + 16;

    hipMemsetAsync(counts, 0, 64, stream);
    hipMemsetAsync(d_out, 0, (size_t)T_TOK * HID * sizeof(float), stream);

    if (fast) {
        convert_kernel<<<2048, 256, 0, stream>>>(gup, gupbf, NEXP * 2 * FDIM * HID / 4);
        convert_kernel<<<2048, 256, 0, stream>>>(dw,  dwbf,  NEXP * HID * FDIM / 4);
    }

    router_kernel<<<T_TOK, 64, 0, stream>>>(x, gw, out + (size_t)T_TOK * HID,
                                            xbf, counts, tokl, wtl);
    prefix_kernel<<<1, 64, 0, stream>>>(counts, offs);

    dim3 g1(FDIM / 128, T_TOK / 128, NEXP);
    dim3 g2(HID / 128, T_TOK / 128, NEXP);
    if (fast) {
        gemm1_kernel<<<g1, 256, 0, stream>>>(xbf, gupbf, h1, counts, offs, tokl);
        gemm2_kernel<<<g2, 256, 0, stream>>>(h1, dwbf, out, counts, offs, tokl, wtl);
    } else {
        gemm1_fb_kernel<<<g1, 256, 0, stream>>>(xbf, gup, h1, counts, offs, tokl);
        gemm2_fb_kernel<<<g2, 256, 0, stream>>>(h1, dw, out, counts, offs, tokl, wtl);
    }
}

// Round 11
// 890.737 us; speedup vs baseline: 1.5426x; 1.0498x over previous
//
#include <hip/hip_runtime.h>
#include <hip/hip_bf16.h>

#define T_TOK 4096
#define HID   1024
#define FDIM  4096
#define NEXP  8

typedef unsigned short u16;
typedef __attribute__((ext_vector_type(8))) __bf16 bf16x8;
typedef __attribute__((ext_vector_type(4))) float  f32x4;

__device__ __forceinline__ u16 f2bf(float f) {
    unsigned u = __float_as_uint(f);
    u += 0x7fffu + ((u >> 16) & 1u);   // RNE; inputs finite
    return (u16)(u >> 16);
}
__device__ __forceinline__ float bf2f(u16 v) {
    return __uint_as_float((unsigned)v << 16);
}

// async global->LDS, 16B per lane. LDS dest is wave-uniform base + lane*16.
__device__ __forceinline__ void gl2lds16(const u16* g, u16* l) {
    __builtin_amdgcn_global_load_lds(
        (const __attribute__((address_space(1))) void*)g,
        (__attribute__((address_space(3))) void*)l, 16, 0, 0);
}

// ---------------------------------------------------------------------------
// plain fp32 -> bf16 convert (down_weights)
// ---------------------------------------------------------------------------
__global__ __launch_bounds__(256) void convert_kernel(
    const float* __restrict__ src, u16* __restrict__ dst, int n4)
{
    const int stride = gridDim.x * blockDim.x;
    for (int i = blockIdx.x * blockDim.x + threadIdx.x; i < n4; i += stride) {
        float4 f = reinterpret_cast<const float4*>(src)[i];
        ushort4 u;
        u.x = f2bf(f.x); u.y = f2bf(f.y); u.z = f2bf(f.z); u.w = f2bf(f.w);
        reinterpret_cast<ushort4*>(dst)[i] = u;
    }
}

// ---------------------------------------------------------------------------
// gate_up convert WITH 16-row interleave:
// dst row r (within expert, r in [0,8192)):
//   mat = (r>>4)&1   (0 = w1/gate, 1 = w3/up)
//   f   = ((r>>5)<<4) | (r&15)
//   src row = mat*FDIM + f
// So a 128-row dst tile = 64 f-cols, alternating 16 gate rows / 16 up rows.
// ---------------------------------------------------------------------------
__global__ __launch_bounds__(256) void convert_gup_kernel(
    const float* __restrict__ src, u16* __restrict__ dst)
{
    const int total = NEXP * 2 * FDIM * (HID / 4);
    const int stride = gridDim.x * blockDim.x;
    for (int i = blockIdx.x * blockDim.x + threadIdx.x; i < total; i += stride) {
        int c = i & 255;              // HID/4 = 256 chunks per row
        int row = i >> 8;
        int e = row >> 13;            // 8192 rows per expert
        int r = row & 8191;
        int mat = (r >> 4) & 1;
        int f = ((r >> 5) << 4) | (r & 15);
        size_t srcIdx = ((((size_t)e << 13) + ((size_t)mat << 12) + (size_t)f) << 8) + c;
        float4 v = reinterpret_cast<const float4*>(src)[srcIdx];
        ushort4 u;
        u.x = f2bf(v.x); u.y = f2bf(v.y); u.z = f2bf(v.z); u.w = f2bf(v.w);
        reinterpret_cast<ushort4*>(dst)[i] = u;
    }
}

// ---------------------------------------------------------------------------
// Router: logits -> d_out, softmax, top-2, scatter lists, x -> bf16,
// and per-token (expert,pos) slot record for the combine pass.
// ---------------------------------------------------------------------------
__global__ __launch_bounds__(64) void router_kernel(
    const float* __restrict__ x, const float* __restrict__ gw,
    float* __restrict__ out_logits, u16* __restrict__ xbf,
    int* __restrict__ counts, int* __restrict__ tokl, float* __restrict__ wtl,
    int4* __restrict__ tokslot)
{
    const int t = blockIdx.x;
    const int lane = threadIdx.x;

    const float4* xr = reinterpret_cast<const float4*>(x + (size_t)t * HID);
    float4 xv[4];
#pragma unroll
    for (int j = 0; j < 4; ++j) xv[j] = xr[lane + 64 * j];

    ushort4* xbr = reinterpret_cast<ushort4*>(xbf + (size_t)t * HID);
#pragma unroll
    for (int j = 0; j < 4; ++j) {
        ushort4 u;
        u.x = f2bf(xv[j].x); u.y = f2bf(xv[j].y);
        u.z = f2bf(xv[j].z); u.w = f2bf(xv[j].w);
        xbr[lane + 64 * j] = u;
    }

    float lg[8];
#pragma unroll
    for (int e = 0; e < 8; ++e) {
        const float4* gr = reinterpret_cast<const float4*>(gw + (size_t)e * HID);
        float s = 0.f;
#pragma unroll
        for (int j = 0; j < 4; ++j) {
            float4 g = gr[lane + 64 * j];
            s += xv[j].x * g.x + xv[j].y * g.y + xv[j].z * g.z + xv[j].w * g.w;
        }
#pragma unroll
        for (int off = 32; off >= 1; off >>= 1) s += __shfl_xor(s, off);
        lg[e] = s;
    }

    if (lane == 0) {
#pragma unroll
        for (int e = 0; e < 8; ++e) out_logits[(size_t)t * 8 + e] = lg[e];
        float m = lg[0];
#pragma unroll
        for (int e = 1; e < 8; ++e) m = fmaxf(m, lg[e]);
        float p[8];
#pragma unroll
        for (int e = 0; e < 8; ++e) p[e] = __expf(lg[e] - m);
        int b0 = 0; float v0 = p[0];
#pragma unroll
        for (int e = 1; e < 8; ++e) { if (p[e] > v0) { v0 = p[e]; b0 = e; } }
        int b1 = -1; float v1 = -1.f;
#pragma unroll
        for (int e = 0; e < 8; ++e) { if (e != b0 && p[e] > v1) { v1 = p[e]; b1 = e; } }
        float inv = 1.f / (v0 + v1);
        int p0 = atomicAdd(&counts[b0], 1);
        tokl[b0 * T_TOK + p0] = t; wtl[b0 * T_TOK + p0] = v0 * inv;
        int p1 = atomicAdd(&counts[b1], 1);
        tokl[b1 * T_TOK + p1] = t; wtl[b1 * T_TOK + p1] = v1 * inv;
        tokslot[t] = make_int4(b0, p0, b1, p1);
    }
}

__global__ void prefix_kernel(const int* __restrict__ counts, int* __restrict__ offs)
{
    if (threadIdx.x == 0 && blockIdx.x == 0) {
        int s = 0;
        for (int e = 0; e < NEXP; ++e) { offs[e] = s; s += counts[e]; }
        offs[NEXP] = s;
    }
}

// ===========================================================================
// FAST GEMM1: 128 gathered rows x 64 f-cols per block, interleaved B tile
// (gate+up in one 128x64 LDS buffer). m97 shape: 2 buffers, 8 gl2lds/wave,
// BK=64, 2-barrier loop, 4 waves 2x2, 16x16x32 bf16 MFMA.
// ===========================================================================
__global__ __launch_bounds__(256, 3) void gemm1_kernel(
    const u16* __restrict__ xbf, const u16* __restrict__ gupbf,
    u16* __restrict__ h1,
    const int* __restrict__ counts, const int* __restrict__ offs,
    const int* __restrict__ tokl)
{
    const int e = blockIdx.z;
    const int cnt = counts[e];
    const int m0 = blockIdx.y * 128;
    if (m0 >= cnt) return;
    const int tid = threadIdx.x;
    const int lane = tid & 63;
    const int wid = tid >> 6;
    const int wr = wid >> 1, wc = wid & 1;
    int cntL = cnt - m0; if (cntL > 128) cntL = 128;

    __shared__ alignas(16) u16 As[128 * 64];
    __shared__ alignas(16) u16 Bs[128 * 64];
    __shared__ int toks[128];

    if (tid < 128)
        toks[tid] = tokl[e * T_TOK + (tid < cntL ? m0 + tid : m0)];
    __syncthreads();

    // B base: interleaved rows [bx*128, bx*128+128) of expert e
    const u16* wB = gupbf + ((size_t)e * 2 * FDIM + (size_t)blockIdx.x * 128) * HID;

    const int lr = lane >> 3;
    const int lc = (lane & 7) * 8;
    int rb[4]; size_t aOff[4], bOff[4];
#pragma unroll
    for (int i = 0; i < 4; ++i) {
        rb[i] = (wid * 4 + i) * 8;
        aOff[i] = (size_t)toks[rb[i] + lr] * HID + lc;
        bOff[i] = (size_t)(rb[i] + lr) * HID + lc;
    }

    f32x4 acc[4][4];
#pragma unroll
    for (int i = 0; i < 4; ++i)
#pragma unroll
        for (int j = 0; j < 4; ++j) acc[i][j] = f32x4{0.f, 0.f, 0.f, 0.f};

    for (int k0 = 0; k0 < HID; k0 += 64) {
#pragma unroll
        for (int i = 0; i < 4; ++i) {
            gl2lds16(xbf + aOff[i] + k0, &As[rb[i] * 64]);
            gl2lds16(wB + bOff[i] + k0, &Bs[rb[i] * 64]);
        }
        __syncthreads();
#pragma unroll
        for (int kk = 0; kk < 64; kk += 32) {
            bf16x8 a[4], b[4];
            const int co = kk + ((lane >> 4) << 3);
#pragma unroll
            for (int f = 0; f < 4; ++f) {
                int ra = wr * 64 + f * 16 + (lane & 15);
                a[f] = *reinterpret_cast<const bf16x8*>(&As[ra * 64 + co]);
                int rq = wc * 64 + f * 16 + (lane & 15);
                b[f] = *reinterpret_cast<const bf16x8*>(&Bs[rq * 64 + co]);
            }
#pragma unroll
            for (int i = 0; i < 4; ++i)
#pragma unroll
                for (int j = 0; j < 4; ++j)
                    acc[i][j] = __builtin_amdgcn_mfma_f32_16x16x32_bf16(a[i], b[j], acc[i][j], 0, 0, 0);
        }
        __syncthreads();
    }

    // epilogue: j = p*2+m, m=0 gate, m=1 up (same f-cols, same lane mapping)
    const size_t hbase = (size_t)offs[e] + m0;
    const int fc0 = blockIdx.x * 64 + wc * 32;
#pragma unroll
    for (int i = 0; i < 4; ++i)
#pragma unroll
        for (int p = 0; p < 2; ++p)
#pragma unroll
            for (int v = 0; v < 4; ++v) {
                int rl = wr * 64 + i * 16 + ((lane >> 4) << 2) + v;
                if (rl < cntL) {
                    float g = acc[i][p * 2][v], u = acc[i][p * 2 + 1][v];
                    float h = (g / (1.f + __expf(-g))) * u;
                    int col = fc0 + p * 16 + (lane & 15);
                    h1[(hbase + rl) * FDIM + col] = f2bf(h);
                }
            }
}

// ===========================================================================
// FAST GEMM2: h2[slot] = w_tok * (H1 W2^T), bf16 store, NO atomics.
// ===========================================================================
__global__ __launch_bounds__(256, 3) void gemm2_kernel(
    const u16* __restrict__ h1, const u16* __restrict__ dwbf,
    u16* __restrict__ h2,
    const int* __restrict__ counts, const int* __restrict__ offs,
    const int* __restrict__ tokl, const float* __restrict__ wtl)
{
    const int e = blockIdx.z;
    const int cnt = counts[e];
    const int m0 = blockIdx.y * 128;
    if (m0 >= cnt) return;
    const int n0 = blockIdx.x * 128;
    const int tid = threadIdx.x;
    const int lane = tid & 63;
    const int wid = tid >> 6;
    const int wr = wid >> 1, wc = wid & 1;
    int cntL = cnt - m0; if (cntL > 128) cntL = 128;

    __shared__ alignas(16) u16 As[128 * 64];
    __shared__ alignas(16) u16 Bs[128 * 64];
    __shared__ float wts[128];

    if (tid < 128)
        wts[tid] = wtl[e * T_TOK + (tid < cntL ? m0 + tid : m0)];
    __syncthreads();

    const size_t hrow0 = (size_t)offs[e] + m0;
    const u16* w2 = dwbf + (size_t)e * HID * FDIM + (size_t)n0 * FDIM;

    const int lr = lane >> 3;
    const int lc = (lane & 7) * 8;
    int rb[4]; size_t aOff[4], bOff[4];
#pragma unroll
    for (int i = 0; i < 4; ++i) {
        rb[i] = (wid * 4 + i) * 8;
        int r = rb[i] + lr; if (r >= cntL) r = cntL - 1;
        aOff[i] = (hrow0 + r) * (size_t)FDIM + lc;
        bOff[i] = (size_t)(rb[i] + lr) * FDIM + lc;
    }

    f32x4 acc[4][4];
#pragma unroll
    for (int i = 0; i < 4; ++i)
#pragma unroll
        for (int j = 0; j < 4; ++j) acc[i][j] = f32x4{0.f, 0.f, 0.f, 0.f};

    for (int k0 = 0; k0 < FDIM; k0 += 64) {
#pragma unroll
        for (int i = 0; i < 4; ++i) {
            gl2lds16(h1 + aOff[i] + k0, &As[rb[i] * 64]);
            gl2lds16(w2 + bOff[i] + k0, &Bs[rb[i] * 64]);
        }
        __syncthreads();
#pragma unroll
        for (int kk = 0; kk < 64; kk += 32) {
            bf16x8 a[4], b[4];
            const int co = kk + ((lane >> 4) << 3);
#pragma unroll
            for (int f = 0; f < 4; ++f) {
                int ra = wr * 64 + f * 16 + (lane & 15);
                a[f] = *reinterpret_cast<const bf16x8*>(&As[ra * 64 + co]);
                int rq = wc * 64 + f * 16 + (lane & 15);
                b[f] = *reinterpret_cast<const bf16x8*>(&Bs[rq * 64 + co]);
            }
#pragma unroll
            for (int i = 0; i < 4; ++i)
#pragma unroll
                for (int j = 0; j < 4; ++j)
                    acc[i][j] = __builtin_amdgcn_mfma_f32_16x16x32_bf16(a[i], b[j], acc[i][j], 0, 0, 0);
        }
        __syncthreads();
    }

#pragma unroll
    for (int i = 0; i < 4; ++i)
#pragma unroll
        for (int j = 0; j < 4; ++j)
#pragma unroll
            for (int v = 0; v < 4; ++v) {
                int rl = wr * 64 + i * 16 + ((lane >> 4) << 2) + v;
                if (rl < cntL) {
                    float w = wts[rl];
                    int cl = wc * 64 + j * 16 + (lane & 15);
                    h2[(hrow0 + rl) * HID + n0 + cl] = f2bf(w * acc[i][j][v]);
                }
            }
}

// ---------------------------------------------------------------------------
// Combine: out[t] = h2[slot0(t)] + h2[slot1(t)]  (fp32 out, fully writes out)
// ---------------------------------------------------------------------------
__global__ __launch_bounds__(256) void combine_kernel(
    const u16* __restrict__ h2, const int4* __restrict__ tokslot,
    const int* __restrict__ offs, float* __restrict__ out)
{
    const int t = blockIdx.x;
    const int lane = threadIdx.x;          // 256 threads x float4 = 1024 cols
    int4 ts = tokslot[t];
    size_t s0 = (size_t)(offs[ts.x] + ts.y) * HID;
    size_t s1 = (size_t)(offs[ts.z] + ts.w) * HID;
    ushort4 a = reinterpret_cast<const ushort4*>(h2 + s0)[lane];
    ushort4 b = reinterpret_cast<const ushort4*>(h2 + s1)[lane];
    float4 o;
    o.x = bf2f(a.x) + bf2f(b.x);
    o.y = bf2f(a.y) + bf2f(b.y);
    o.z = bf2f(a.z) + bf2f(b.z);
    o.w = bf2f(a.w) + bf2f(b.w);
    reinterpret_cast<float4*>(out + (size_t)t * HID)[lane] = o;
}

// ===========================================================================
// FALLBACK PATH (round-1 validated): fp32 weights in-GEMM, swizzled LDS,
// atomic epilogue. Used only if ws_size can't fit bf16 copies.
// ===========================================================================
__global__ __launch_bounds__(256, 2) void gemm1_fb_kernel(
    const u16* __restrict__ xbf, const float* __restrict__ gup,
    u16* __restrict__ h1,
    const int* __restrict__ counts, const int* __restrict__ offs,
    const int* __restrict__ tokl)
{
    const int e = blockIdx.z;
    const int cnt = counts[e];
    const int m0 = blockIdx.y * 128;
    if (m0 >= cnt) return;
    const int n0 = blockIdx.x * 128;
    const int tid = threadIdx.x;
    const int lane = tid & 63;
    const int wid = tid >> 6;
    const int wr = wid >> 1, wc = wid & 1;
    int cntL = cnt - m0; if (cntL > 128) cntL = 128;

    __shared__ alignas(16) u16 As[128 * 64];
    __shared__ alignas(16) u16 B1s[128 * 64];
    __shared__ alignas(16) u16 B3s[128 * 64];
    __shared__ int toks[128];

    if (tid < 128)
        toks[tid] = tokl[e * T_TOK + (tid < cntL ? m0 + tid : m0)];
    __syncthreads();

    const float* w1 = gup + ((size_t)e * 2 * FDIM + n0) * HID;
    const float* w3 = w1 + (size_t)FDIM * HID;

    f32x4 accg[4][4], accu[4][4];
#pragma unroll
    for (int i = 0; i < 4; ++i)
#pragma unroll
        for (int j = 0; j < 4; ++j) { accg[i][j] = f32x4{0.f,0.f,0.f,0.f}; accu[i][j] = f32x4{0.f,0.f,0.f,0.f}; }

    for (int k0 = 0; k0 < HID; k0 += 64) {
#pragma unroll
        for (int i = 0; i < 4; ++i) {
            int idx = tid + i * 256;
            int row = idx >> 3, c = idx & 7;
            const u16* src = xbf + (size_t)toks[row] * HID + k0 + c * 8;
            int dst = row * 128 + ((c * 16) ^ ((row & 7) << 4));
            *reinterpret_cast<int4*>(reinterpret_cast<char*>(As) + dst) =
                *reinterpret_cast<const int4*>(src);
        }
#pragma unroll
        for (int i = 0; i < 8; ++i) {
            int idx = tid + i * 256;
            int row = idx >> 4, c4 = idx & 15;
            const float4 f1 = *reinterpret_cast<const float4*>(w1 + (size_t)row * HID + k0 + c4 * 4);
            const float4 f3 = *reinterpret_cast<const float4*>(w3 + (size_t)row * HID + k0 + c4 * 4);
            ushort4 u1; u1.x = f2bf(f1.x); u1.y = f2bf(f1.y); u1.z = f2bf(f1.z); u1.w = f2bf(f1.w);
            ushort4 u3; u3.x = f2bf(f3.x); u3.y = f2bf(f3.y); u3.z = f2bf(f3.z); u3.w = f2bf(f3.w);
            int dst = row * 128 + ((c4 * 8) ^ ((row & 7) << 4));
            *reinterpret_cast<ushort4*>(reinterpret_cast<char*>(B1s) + dst) = u1;
            *reinterpret_cast<ushort4*>(reinterpret_cast<char*>(B3s) + dst) = u3;
        }
        __syncthreads();
#pragma unroll
        for (int kk = 0; kk < 64; kk += 32) {
            bf16x8 a[4], b1[4], b3[4];
            const int colb = (kk + ((lane >> 4) << 3)) * 2;
#pragma unroll
            for (int f = 0; f < 4; ++f) {
                int ra = wr * 64 + f * 16 + (lane & 15);
                a[f] = *reinterpret_cast<const bf16x8*>(reinterpret_cast<const char*>(As) + ra * 128 + (colb ^ ((ra & 7) << 4)));
                int rq = wc * 64 + f * 16 + (lane & 15);
                b1[f] = *reinterpret_cast<const bf16x8*>(reinterpret_cast<const char*>(B1s) + rq * 128 + (colb ^ ((rq & 7) << 4)));
                b3[f] = *reinterpret_cast<const bf16x8*>(reinterpret_cast<const char*>(B3s) + rq * 128 + (colb ^ ((rq & 7) << 4)));
            }
#pragma unroll
            for (int i = 0; i < 4; ++i)
#pragma unroll
                for (int j = 0; j < 4; ++j) {
                    accg[i][j] = __builtin_amdgcn_mfma_f32_16x16x32_bf16(a[i], b1[j], accg[i][j], 0, 0, 0);
                    accu[i][j] = __builtin_amdgcn_mfma_f32_16x16x32_bf16(a[i], b3[j], accu[i][j], 0, 0, 0);
                }
        }
        __syncthreads();
    }

    const size_t hbase = (size_t)offs[e] + m0;
#pragma unroll
    for (int i = 0; i < 4; ++i)
#pragma unroll
        for (int j = 0; j < 4; ++j)
#pragma unroll
            for (int v = 0; v < 4; ++v) {
                int rl = wr * 64 + i * 16 + ((lane >> 4) << 2) + v;
                if (rl < cntL) {
                    float g = accg[i][j][v], u = accu[i][j][v];
                    float h = (g / (1.f + __expf(-g))) * u;
                    int cl = wc * 64 + j * 16 + (lane & 15);
                    h1[(hbase + rl) * FDIM + n0 + cl] = f2bf(h);
                }
            }
}

__global__ __launch_bounds__(256, 2) void gemm2_fb_kernel(
    const u16* __restrict__ h1, const float* __restrict__ dw,
    float* __restrict__ out,
    const int* __restrict__ counts, const int* __restrict__ offs,
    const int* __restrict__ tokl, const float* __restrict__ wtl)
{
    const int e = blockIdx.z;
    const int cnt = counts[e];
    const int m0 = blockIdx.y * 128;
    if (m0 >= cnt) return;
    const int n0 = blockIdx.x * 128;
    const int tid = threadIdx.x;
    const int lane = tid & 63;
    const int wid = tid >> 6;
    const int wr = wid >> 1, wc = wid & 1;
    int cntL = cnt - m0; if (cntL > 128) cntL = 128;

    __shared__ alignas(16) u16 As[128 * 64];
    __shared__ alignas(16) u16 Bs[128 * 64];
    __shared__ int toks[128];
    __shared__ float wts[128];

    if (tid < 128) {
        int r = (tid < cntL ? m0 + tid : m0);
        toks[tid] = tokl[e * T_TOK + r];
        wts[tid]  = wtl[e * T_TOK + r];
    }
    __syncthreads();

    const size_t hrow0 = (size_t)offs[e] + m0;
    const float* w2 = dw + (size_t)e * HID * FDIM + (size_t)n0 * FDIM;

    f32x4 acc[4][4];
#pragma unroll
    for (int i = 0; i < 4; ++i)
#pragma unroll
        for (int j = 0; j < 4; ++j) acc[i][j] = f32x4{0.f,0.f,0.f,0.f};

    for (int k0 = 0; k0 < FDIM; k0 += 64) {
#pragma unroll
        for (int i = 0; i < 4; ++i) {
            int idx = tid + i * 256;
            int row = idx >> 3, c = idx & 7;
            int rr = (row < cntL ? row : 0);
            const u16* src = h1 + (hrow0 + rr) * FDIM + k0 + c * 8;
            int dst = row * 128 + ((c * 16) ^ ((row & 7) << 4));
            *reinterpret_cast<int4*>(reinterpret_cast<char*>(As) + dst) =
                *reinterpret_cast<const int4*>(src);
        }
#pragma unroll
        for (int i = 0; i < 8; ++i) {
            int idx = tid + i * 256;
            int row = idx >> 4, c4 = idx & 15;
            const float4 f = *reinterpret_cast<const float4*>(w2 + (size_t)row * FDIM + k0 + c4 * 4);
            ushort4 u; u.x = f2bf(f.x); u.y = f2bf(f.y); u.z = f2bf(f.z); u.w = f2bf(f.w);
            int dst = row * 128 + ((c4 * 8) ^ ((row & 7) << 4));
            *reinterpret_cast<ushort4*>(reinterpret_cast<char*>(Bs) + dst) = u;
        }
        __syncthreads();
#pragma unroll
        for (int kk = 0; kk < 64; kk += 32) {
            bf16x8 a[4], b[4];
            const int colb = (kk + ((lane >> 4) << 3)) * 2;
#pragma unroll
            for (int f = 0; f < 4; ++f) {
                int ra = wr * 64 + f * 16 + (lane & 15);
                a[f] = *reinterpret_cast<const bf16x8*>(reinterpret_cast<const char*>(As) + ra * 128 + (colb ^ ((ra & 7) << 4)));
                int rq = wc * 64 + f * 16 + (lane & 15);
                b[f] = *reinterpret_cast<const bf16x8*>(reinterpret_cast<const char*>(Bs) + rq * 128 + (colb ^ ((rq & 7) << 4)));
            }
#pragma unroll
            for (int i = 0; i < 4; ++i)
#pragma unroll
                for (int j = 0; j < 4; ++j)
                    acc[i][j] = __builtin_amdgcn_mfma_f32_16x16x32_bf16(a[i], b[j], acc[i][j], 0, 0, 0);
        }
        __syncthreads();
    }

#pragma unroll
    for (int i = 0; i < 4; ++i)
#pragma unroll
        for (int j = 0; j < 4; ++j)
#pragma unroll
            for (int v = 0; v < 4; ++v) {
                int rl = wr * 64 + i * 16 + ((lane >> 4) << 2) + v;
                if (rl < cntL) {
                    int t = toks[rl];
                    float w = wts[rl];
                    int cl = wc * 64 + j * 16 + (lane & 15);
                    atomicAdd(&out[(size_t)t * HID + n0 + cl], w * acc[i][j][v]);
                }
            }
}

// ---------------------------------------------------------------------------
extern "C" void kernel_launch(void* const* d_in, const int* in_sizes, int n_in,
                              void* d_out, int out_size, void* d_ws, size_t ws_size,
                              hipStream_t stream)
{
    const float* x   = (const float*)d_in[0];
    const float* gw  = (const float*)d_in[1];
    const float* gup = (const float*)d_in[2];
    const float* dw  = (const float*)d_in[3];
    float* out = (float*)d_out;

    const size_t FAST_NEED = ((size_t)264 << 20) + (512u << 10);
    const bool fast = ws_size >= FAST_NEED;

    char* ws = (char*)d_ws;
    u16* xbf   = (u16*)ws;                              // 8 MiB
    u16* h1    = (u16*)(ws + ((size_t)8 << 20));        // 64 MiB
    u16* gupbf = (u16*)(ws + ((size_t)72 << 20));       // 128 MiB (fast only)
    u16* dwbf  = (u16*)(ws + ((size_t)200 << 20));      // 64 MiB  (fast only)
    u16* h2    = gupbf;                                 // 16 MiB overlay; gupbf dead after gemm1
    size_t ctrl = fast ? ((size_t)264 << 20) : ((size_t)72 << 20);
    int*   tokl    = (int*)(ws + ctrl);                  // 128 KiB
    float* wtl     = (float*)(ws + ctrl + (128u << 10)); // 128 KiB
    int*   counts  = (int*)(ws + ctrl + (256u << 10));
    int*   offs    = counts + 16;
    int4*  tokslot = (int4*)(ws + ctrl + (320u << 10));  // 64 KiB

    hipMemsetAsync(counts, 0, 64, stream);

    if (fast) {
        convert_gup_kernel<<<2048, 256, 0, stream>>>(gup, gupbf);
        convert_kernel<<<2048, 256, 0, stream>>>(dw, dwbf, NEXP * HID * FDIM / 4);
    } else {
        hipMemsetAsync(d_out, 0, (size_t)T_TOK * HID * sizeof(float), stream);
    }

    router_kernel<<<T_TOK, 64, 0, stream>>>(x, gw, out + (size_t)T_TOK * HID,
                                            xbf, counts, tokl, wtl, tokslot);
    prefix_kernel<<<1, 64, 0, stream>>>(counts, offs);

    if (fast) {
        dim3 g1(FDIM / 64, T_TOK / 128, NEXP);
        gemm1_kernel<<<g1, 256, 0, stream>>>(xbf, gupbf, h1, counts, offs, tokl);
        dim3 g2(HID / 128, T_TOK / 128, NEXP);
        gemm2_kernel<<<g2, 256, 0, stream>>>(h1, dwbf, h2, counts, offs, tokl, wtl);
        combine_kernel<<<T_TOK, 256, 0, stream>>>(h2, tokslot, offs, out);
    } else {
        dim3 g1(FDIM / 128, T_TOK / 128, NEXP);
        gemm1_fb_kernel<<<g1, 256, 0, stream>>>(xbf, gup, h1, counts, offs, tokl);
        dim3 g2(HID / 128, T_TOK / 128, NEXP);
        gemm2_fb_kernel<<<g2, 256, 0, stream>>>(h1, dw, out, counts, offs, tokl, wtl);
    }
}